// Round 1
// baseline (196.778 us; speedup 1.0000x reference)
//
#include <hip/hip_runtime.h>
#include <math.h>

#define Ec 256
#define Sc 512
#define Bc 2
#define Hc 8
#define Dc 32
#define NROW 4
#define MAXNORM (1.0f - 1e-5f)

__device__ __forceinline__ float fullWaveSum(float v) {
#pragma unroll
  for (int m = 32; m >= 1; m >>= 1) v += __shfl_xor(v, m, 64);
  return v;
}

// sum within 32-lane half-wave (head group)
__device__ __forceinline__ float halfWaveSum(float v) {
#pragma unroll
  for (int m = 16; m >= 1; m >>= 1) v += __shfl_xor(v, m, 64);
  return v;
}

// K1: q/k/v = hyp_linear(W, b, x); clamp q,k; qn/kn per head; lv = logmap0(v)
__global__ __launch_bounds__(256) void qkv_kernel(
    const float* __restrict__ x,
    const float* __restrict__ Wq, const float* __restrict__ bq,
    const float* __restrict__ Wk, const float* __restrict__ bk,
    const float* __restrict__ Wv, const float* __restrict__ bv,
    float* __restrict__ qo, float* __restrict__ ko, float* __restrict__ lvo,
    float* __restrict__ qno, float* __restrict__ kno) {
  const int t = threadIdx.x;
  const int row0 = blockIdx.x * NROW;
  __shared__ float4 xs[NROW][Ec / 4];
  __shared__ float red[31][4];
  __shared__ float fin[31];

  float xv[NROW];
#pragma unroll
  for (int r = 0; r < NROW; ++r) {
    float v = x[(row0 + r) * Ec + t];
    xv[r] = v;
    ((float*)&xs[r][0])[t] = v;
  }
  __syncthreads();

  float acc[3][NROW];
#pragma unroll
  for (int m = 0; m < 3; ++m)
#pragma unroll
    for (int r = 0; r < NROW; ++r) acc[m][r] = 0.0f;

  const float4* W0 = (const float4*)Wq;
  const float4* W1 = (const float4*)Wk;
  const float4* W2 = (const float4*)Wv;
  const int wbase = t * (Ec / 4);
#pragma unroll 4
  for (int kc = 0; kc < Ec / 4; ++kc) {
    float4 w0 = W0[wbase + kc];
    float4 w1 = W1[wbase + kc];
    float4 w2 = W2[wbase + kc];
#pragma unroll
    for (int r = 0; r < NROW; ++r) {
      float4 xc = xs[r][kc];
      acc[0][r] = fmaf(xc.w, w0.w, fmaf(xc.z, w0.z, fmaf(xc.y, w0.y, fmaf(xc.x, w0.x, acc[0][r]))));
      acc[1][r] = fmaf(xc.w, w1.w, fmaf(xc.z, w1.z, fmaf(xc.y, w1.y, fmaf(xc.x, w1.x, acc[1][r]))));
      acc[2][r] = fmaf(xc.w, w2.w, fmaf(xc.z, w2.z, fmaf(xc.y, w2.y, fmaf(xc.x, w2.x, acc[2][r]))));
    }
  }

  float bb[3] = {bq[t], bk[t], bv[t]};

  // 31 block-wide sums: x2[4]; per matrix: mx2[4], mx*b[4], b2[1]
  float vals[31];
#pragma unroll
  for (int r = 0; r < NROW; ++r) vals[r] = xv[r] * xv[r];
#pragma unroll
  for (int m = 0; m < 3; ++m) {
#pragma unroll
    for (int r = 0; r < NROW; ++r) {
      vals[4 + m * 9 + r] = acc[m][r] * acc[m][r];
      vals[4 + m * 9 + 4 + r] = acc[m][r] * bb[m];
    }
    vals[4 + m * 9 + 8] = bb[m] * bb[m];
  }
#pragma unroll
  for (int i = 0; i < 31; ++i) {
    float v = fullWaveSum(vals[i]);
    if ((t & 63) == 0) red[i][t >> 6] = v;
  }
  __syncthreads();
  if (t < 31) fin[t] = red[t][0] + red[t][1] + red[t][2] + red[t][3];
  __syncthreads();

  const int h = t >> 5;
#pragma unroll
  for (int m = 0; m < 3; ++m) {
#pragma unroll
    for (int r = 0; r < NROW; ++r) {
      const int row = row0 + r;
      const int b = row >> 9;        // S = 512
      const int s = row & (Sc - 1);
      float x2 = fin[r];
      float mx2 = fin[4 + m * 9 + r];
      float mxb = fin[4 + m * 9 + 4 + r];
      float b2 = fin[4 + m * 9 + 8];
      float xn = sqrtf(fmaxf(x2, 1e-15f));
      float mxn = sqrtf(fmaxf(mx2, 1e-15f));
      float arg = fminf(xn, MAXNORM);                 // SC = 1
      float scl = tanhf((mxn / xn) * atanhf(arg)) / mxn;
      float mv = scl * acc[m][r];                     // mobius_matvec result elem
      // mobius_add(mv_row, b)
      float X2 = scl * scl * mx2;
      float XY = scl * mxb;
      float numc = 1.0f + 2.0f * XY + b2;
      float den = 1.0f + 2.0f * XY + X2 * b2 + 1e-15f;
      float res = (numc * mv + (1.0f - X2) * bb[m]) / den;
      if (m < 2) {
        res = fminf(res, MAXNORM);                    // elementwise clamp_max
        float s2 = halfWaveSum(res * res);            // per-head norm^2 (C=1)
        if (m == 0) {
          qo[row * Ec + t] = res;
          if ((t & 31) == 0) qno[(b * Hc + h) * Sc + s] = s2;
        } else {
          ko[row * Ec + t] = res;
          if ((t & 31) == 0) kno[(b * Hc + h) * Sc + s] = s2;
        }
      } else {
        // logmap0 per head slice
        float vn2 = halfWaveSum(res * res);
        float vn = sqrtf(fmaxf(vn2, 1e-15f));
        float f = atanhf(fminf(vn, MAXNORM)) / vn;
        lvo[row * Ec + t] = f * res;
      }
    }
  }
}

// K2: fused hyperbolic-distance attention + online softmax + expmap0
// grid: b*128 + h*16 + qtile ; block 256: r = tid&31 (q row in tile), g = tid>>5 (j-split)
__global__ __launch_bounds__(256) void attn_kernel(
    const float* __restrict__ q, const float* __restrict__ k,
    const float* __restrict__ lv, const float* __restrict__ qn,
    const float* __restrict__ kn, const float* __restrict__ hs,
    float* __restrict__ out) {
  const int tid = threadIdx.x;
  const int r = tid & 31;
  const int g = tid >> 5;
  const int blk = blockIdx.x;
  const int qt = blk & 15;
  const int h = (blk >> 4) & 7;
  const int b = blk >> 7;
  const int sq = qt * 32 + r;

  const float* qrow = q + (size_t)(b * Sc + sq) * Ec + h * Dc;
  float4 qv[8];
#pragma unroll
  for (int i = 0; i < 8; ++i) qv[i] = ((const float4*)qrow)[i];
  const float q2 = qn[(b * Hc + h) * Sc + sq];
  const float sinv = -1.0f / (hs[h] * sqrtf((float)Dc));

  const float* kb = k + (size_t)(b * Sc) * Ec + h * Dc;
  const float* lvb = lv + (size_t)(b * Sc) * Ec + h * Dc;
  const float* knp = kn + (b * Hc + h) * Sc;

  float mM = -1e30f, lS = 0.0f;
  float4 acc4[8];
#pragma unroll
  for (int i = 0; i < 8; ++i) acc4[i] = make_float4(0.f, 0.f, 0.f, 0.f);

  for (int jj = 0; jj < 64; ++jj) {
    const int j = g * 64 + jj;
    const float4* kr = (const float4*)(kb + (size_t)j * Ec);
    const float4* lr = (const float4*)(lvb + (size_t)j * Ec);
    float4 kv[8], lvv[8];
#pragma unroll
    for (int i = 0; i < 8; ++i) kv[i] = kr[i];
#pragma unroll
    for (int i = 0; i < 8; ++i) lvv[i] = lr[i];
    float kq = 0.0f;
#pragma unroll
    for (int i = 0; i < 8; ++i) {
      kq = fmaf(qv[i].x, kv[i].x, kq);
      kq = fmaf(qv[i].y, kv[i].y, kq);
      kq = fmaf(qv[i].z, kv[i].z, kq);
      kq = fmaf(qv[i].w, kv[i].w, kq);
    }
    float k2 = knp[j];
    // dn = ||mobius_add(-k, q)||^2 from scalars
    float A = 1.0f - 2.0f * kq + q2;
    float Bv = 1.0f - k2;
    float dden = 1.0f - 2.0f * kq + k2 * q2 + 1e-15f;
    float di = 1.0f / dden;
    float num2 = (A * A) * k2 - 2.0f * A * Bv * kq + (Bv * Bv) * q2;
    float dn = num2 * di * di;
    float denom = (1.0f - q2) * (1.0f - k2) + 1e-15f;
    float tt = fmaxf(2.0f * dn / denom, 1e-7f);       // a - 1, cancellation-free
    float dist = log1pf(tt + sqrtf(tt * (2.0f + tt))); // acosh(1+tt)
    float sc = dist * sinv;
    // online softmax (branchless)
    float mn = fmaxf(mM, sc);
    float alpha = expf(mM - mn);
    float p = expf(sc - mn);
    lS = fmaf(lS, alpha, p);
#pragma unroll
    for (int i = 0; i < 8; ++i) {
      acc4[i].x = fmaf(acc4[i].x, alpha, p * lvv[i].x);
      acc4[i].y = fmaf(acc4[i].y, alpha, p * lvv[i].y);
      acc4[i].z = fmaf(acc4[i].z, alpha, p * lvv[i].z);
      acc4[i].w = fmaf(acc4[i].w, alpha, p * lvv[i].w);
    }
    mM = mn;
  }

  // merge 8 partials per row
  __shared__ float accb[32][8][32];
  __shared__ float2 mlb[32][8];
  __shared__ float cw[32][8];
  __shared__ float linvb[32];
  __shared__ float rowred[32][8];
  __shared__ float fscb[32];

  float* ap = &accb[r][g][0];
#pragma unroll
  for (int i = 0; i < 8; ++i) ((float4*)ap)[i] = acc4[i];
  mlb[r][g] = make_float2(mM, lS);
  __syncthreads();

  if (g == 0) {
    float M = mlb[r][0].x;
#pragma unroll
    for (int gg = 1; gg < 8; ++gg) M = fmaxf(M, mlb[r][gg].x);
    float L = 0.0f;
#pragma unroll
    for (int gg = 0; gg < 8; ++gg) {
      float wgt = expf(mlb[r][gg].x - M);
      cw[r][gg] = wgt;
      L = fmaf(mlb[r][gg].y, wgt, L);
    }
    linvb[r] = 1.0f / L;
  }
  __syncthreads();

  // thread (r,g) merges d = g*4 .. g*4+3
  float o[4] = {0.f, 0.f, 0.f, 0.f};
#pragma unroll
  for (int gg = 0; gg < 8; ++gg) {
    float wgt = cw[r][gg];
#pragma unroll
    for (int d0 = 0; d0 < 4; ++d0) o[d0] = fmaf(accb[r][gg][g * 4 + d0], wgt, o[d0]);
  }
  float li = linvb[r];
  float ssq = 0.0f;
#pragma unroll
  for (int d0 = 0; d0 < 4; ++d0) {
    o[d0] *= li;
    ssq = fmaf(o[d0], o[d0], ssq);
  }
  rowred[r][g] = ssq;
  __syncthreads();
  if (g == 0) {
    float un2 = 0.0f;
#pragma unroll
    for (int gg = 0; gg < 8; ++gg) un2 += rowred[r][gg];
    float un = sqrtf(fmaxf(un2, 1e-15f));
    fscb[r] = tanhf(un) / un;   // expmap0 factor (SC = 1)
  }
  __syncthreads();
  float f = fscb[r];
  float* orow = out + (size_t)(b * Sc + sq) * Ec + h * Dc + g * 4;
#pragma unroll
  for (int d0 = 0; d0 < 4; ++d0) orow[d0] = o[d0] * f;
}

// K3: out = hyp_linear(Wo, bo, attn_out)
__global__ __launch_bounds__(256) void proj_kernel(
    const float* __restrict__ xin, const float* __restrict__ Wo,
    const float* __restrict__ bo, float* __restrict__ out) {
  const int t = threadIdx.x;
  const int row0 = blockIdx.x * NROW;
  __shared__ float4 xs[NROW][Ec / 4];
  __shared__ float red[13][4];
  __shared__ float fin[13];

  float xv[NROW];
#pragma unroll
  for (int r = 0; r < NROW; ++r) {
    float v = xin[(row0 + r) * Ec + t];
    xv[r] = v;
    ((float*)&xs[r][0])[t] = v;
  }
  __syncthreads();

  float acc[NROW];
#pragma unroll
  for (int r = 0; r < NROW; ++r) acc[r] = 0.0f;
  const float4* W0 = (const float4*)Wo;
  const int wbase = t * (Ec / 4);
#pragma unroll 4
  for (int kc = 0; kc < Ec / 4; ++kc) {
    float4 w0 = W0[wbase + kc];
#pragma unroll
    for (int r = 0; r < NROW; ++r) {
      float4 xc = xs[r][kc];
      acc[r] = fmaf(xc.w, w0.w, fmaf(xc.z, w0.z, fmaf(xc.y, w0.y, fmaf(xc.x, w0.x, acc[r]))));
    }
  }
  float bb = bo[t];
  float vals[13];
#pragma unroll
  for (int r = 0; r < NROW; ++r) {
    vals[r] = xv[r] * xv[r];
    vals[4 + r] = acc[r] * acc[r];
    vals[8 + r] = acc[r] * bb;
  }
  vals[12] = bb * bb;
#pragma unroll
  for (int i = 0; i < 13; ++i) {
    float v = fullWaveSum(vals[i]);
    if ((t & 63) == 0) red[i][t >> 6] = v;
  }
  __syncthreads();
  if (t < 13) fin[t] = red[t][0] + red[t][1] + red[t][2] + red[t][3];
  __syncthreads();

#pragma unroll
  for (int r = 0; r < NROW; ++r) {
    const int row = row0 + r;
    float x2 = fin[r];
    float mx2 = fin[4 + r];
    float mxb = fin[8 + r];
    float b2 = fin[12];
    float xn = sqrtf(fmaxf(x2, 1e-15f));
    float mxn = sqrtf(fmaxf(mx2, 1e-15f));
    float arg = fminf(xn, MAXNORM);
    float scl = tanhf((mxn / xn) * atanhf(arg)) / mxn;
    float mv = scl * acc[r];
    float X2 = scl * scl * mx2;
    float XY = scl * mxb;
    float numc = 1.0f + 2.0f * XY + b2;
    float den = 1.0f + 2.0f * XY + X2 * b2 + 1e-15f;
    out[row * Ec + t] = (numc * mv + (1.0f - X2) * bb) / den;
  }
}

extern "C" void kernel_launch(void* const* d_in, const int* in_sizes, int n_in,
                              void* d_out, int out_size, void* d_ws, size_t ws_size,
                              hipStream_t stream) {
  (void)in_sizes; (void)n_in; (void)out_size; (void)ws_size;
  const float* x  = (const float*)d_in[0];
  const float* Wq = (const float*)d_in[1];
  const float* bq = (const float*)d_in[2];
  const float* Wk = (const float*)d_in[3];
  const float* bk = (const float*)d_in[4];
  const float* Wv = (const float*)d_in[5];
  const float* bv = (const float*)d_in[6];
  const float* Wo = (const float*)d_in[7];
  const float* bo = (const float*)d_in[8];
  const float* hs = (const float*)d_in[9];

  float* ws = (float*)d_ws;
  const int NE = Bc * Sc * Ec;   // 262144
  const int NH = Bc * Hc * Sc;   // 8192
  float* qb  = ws;
  float* kb  = qb + NE;
  float* lvb = kb + NE;
  float* qnb = lvb + NE;
  float* knb = qnb + NH;
  float* aob = knb + NH;

  qkv_kernel<<<(Bc * Sc) / NROW, 256, 0, stream>>>(x, Wq, bq, Wk, bk, Wv, bv,
                                                   qb, kb, lvb, qnb, knb);
  attn_kernel<<<Bc * Hc * (Sc / 32), 256, 0, stream>>>(qb, kb, lvb, qnb, knb, hs, aob);
  proj_kernel<<<(Bc * Sc) / NROW, 256, 0, stream>>>(aob, Wo, bo, (float*)d_out);
}

// Round 2
// 158.640 us; speedup vs baseline: 1.2404x; 1.2404x over previous
//
#include <hip/hip_runtime.h>
#include <math.h>

#define Ec 256
#define Sc 512
#define Bc 2
#define Hc 8
#define Dc 32
#define MAXNORM (1.0f - 1e-5f)

__device__ __forceinline__ float fullWaveSum(float v) {
#pragma unroll
  for (int m = 32; m >= 1; m >>= 1) v += __shfl_xor(v, m, 64);
  return v;
}

// sum within 32-lane half-wave (head group)
__device__ __forceinline__ float halfWaveSum(float v) {
#pragma unroll
  for (int m = 16; m >= 1; m >>= 1) v += __shfl_xor(v, m, 64);
  return v;
}

// ---------------------------------------------------------------------------
// Tiled GEMM: O[mat] = X @ W[mat]^T.  Tile 32 rows x 64 cols, K-chunk 64.
// grid (M/32, 4*nmat), block 128.  mat = by>>2, col tile = by&3.
// LDS stores both tiles K-major (transposed) so compute reads are float4
// along the row/col dim and conflict-free; staging writes are scalar
// (minor conflicts, 1/16 of instruction count).
// ---------------------------------------------------------------------------
__global__ __launch_bounds__(128) void gemm_xwt(
    const float* __restrict__ X,
    const float* __restrict__ W0, const float* __restrict__ W1,
    const float* __restrict__ W2,
    float* __restrict__ O0, float* __restrict__ O1, float* __restrict__ O2) {
  const int tid = threadIdx.x;
  const int bx = blockIdx.x;
  const int by = blockIdx.y;
  const int mat = by >> 2;
  const int cb0 = (by & 3) * 64;
  const int rb0 = bx * 32;
  const float* __restrict__ W = (mat == 0) ? W0 : (mat == 1) ? W1 : W2;
  float* __restrict__ O = (mat == 0) ? O0 : (mat == 1) ? O1 : O2;

  __shared__ float Xs[64][36];   // [k][row], pad 36 keeps float4 align
  __shared__ float Ws[64][68];   // [k][col]

  const int f4 = tid & 15;       // float4 index along K
  const int sub = tid >> 4;      // 0..7
  const int ty = tid >> 4;       // row group: rows ty*4..ty*4+3
  const int tx = tid & 15;       // col group: cols tx*4..tx*4+3

  float acc[4][4];
#pragma unroll
  for (int i = 0; i < 4; ++i)
#pragma unroll
    for (int j = 0; j < 4; ++j) acc[i][j] = 0.f;

  for (int kk = 0; kk < Ec; kk += 64) {
    __syncthreads();
#pragma unroll
    for (int i = 0; i < 4; ++i) {
      int row = sub + i * 8;
      float4 v = *(const float4*)&X[(size_t)(rb0 + row) * Ec + kk + f4 * 4];
      Xs[f4 * 4 + 0][row] = v.x;
      Xs[f4 * 4 + 1][row] = v.y;
      Xs[f4 * 4 + 2][row] = v.z;
      Xs[f4 * 4 + 3][row] = v.w;
    }
#pragma unroll
    for (int i = 0; i < 8; ++i) {
      int col = sub + i * 8;
      float4 v = *(const float4*)&W[(size_t)(cb0 + col) * Ec + kk + f4 * 4];
      Ws[f4 * 4 + 0][col] = v.x;
      Ws[f4 * 4 + 1][col] = v.y;
      Ws[f4 * 4 + 2][col] = v.z;
      Ws[f4 * 4 + 3][col] = v.w;
    }
    __syncthreads();
#pragma unroll 8
    for (int k = 0; k < 64; ++k) {
      float4 a = *(const float4*)&Xs[k][ty * 4];
      float4 b = *(const float4*)&Ws[k][tx * 4];
      float av[4] = {a.x, a.y, a.z, a.w};
      float bv[4] = {b.x, b.y, b.z, b.w};
#pragma unroll
      for (int i = 0; i < 4; ++i)
#pragma unroll
        for (int j = 0; j < 4; ++j) acc[i][j] = fmaf(av[i], bv[j], acc[i][j]);
    }
  }
#pragma unroll
  for (int i = 0; i < 4; ++i) {
    float4 o = make_float4(acc[i][0], acc[i][1], acc[i][2], acc[i][3]);
    *(float4*)&O[(size_t)(rb0 + ty * 4 + i) * Ec + cb0 + tx * 4] = o;
  }
}

// ---------------------------------------------------------------------------
// Per-row hyp_linear epilogue for q/k/v: one block per row.
// mobius_matvec scale + mobius_add(.,b) + clamp + per-head norms + logmap0(v)
// ---------------------------------------------------------------------------
__global__ __launch_bounds__(256) void qkv_stats(
    const float* __restrict__ x,
    const float* __restrict__ mxq, const float* __restrict__ mxk,
    const float* __restrict__ mxv,
    const float* __restrict__ bq, const float* __restrict__ bk,
    const float* __restrict__ bv,
    float* __restrict__ qo, float* __restrict__ ko, float* __restrict__ lvo,
    float* __restrict__ qno, float* __restrict__ kno) {
  const int t = threadIdx.x;
  const int row = blockIdx.x;
  const int b = row >> 9;
  const int s = row & (Sc - 1);
  const float xv = x[(size_t)row * Ec + t];
  const float mq = mxq[(size_t)row * Ec + t];
  const float mk = mxk[(size_t)row * Ec + t];
  const float mv = mxv[(size_t)row * Ec + t];
  const float bb[3] = {bq[t], bk[t], bv[t]};
  const float mvals[3] = {mq, mk, mv};

  float vals[10] = {xv * xv,
                    mq * mq, mq * bb[0], bb[0] * bb[0],
                    mk * mk, mk * bb[1], bb[1] * bb[1],
                    mv * mv, mv * bb[2], bb[2] * bb[2]};
  __shared__ float red[10][4];
  __shared__ float fin[10];
#pragma unroll
  for (int i = 0; i < 10; ++i) {
    float v = fullWaveSum(vals[i]);
    if ((t & 63) == 0) red[i][t >> 6] = v;
  }
  __syncthreads();
  if (t < 10) fin[t] = red[t][0] + red[t][1] + red[t][2] + red[t][3];
  __syncthreads();

  const float x2 = fin[0];
  const float xn = sqrtf(fmaxf(x2, 1e-15f));
  const float at = atanhf(fminf(xn, MAXNORM));  // SC = 1
  const int h = t >> 5;

#pragma unroll
  for (int m = 0; m < 3; ++m) {
    float mx2 = fin[1 + 3 * m];
    float mxb = fin[2 + 3 * m];
    float b2 = fin[3 + 3 * m];
    float mxn = sqrtf(fmaxf(mx2, 1e-15f));
    float scl = tanhf((mxn / xn) * at) / mxn;
    float mvv = scl * mvals[m];
    float X2 = scl * scl * mx2;
    float XY = scl * mxb;
    float numc = 1.0f + 2.0f * XY + b2;
    float den = 1.0f + 2.0f * XY + X2 * b2 + 1e-15f;
    float res = (numc * mvv + (1.0f - X2) * bb[m]) / den;
    if (m < 2) {
      res = fminf(res, MAXNORM);                 // elementwise clamp_max
      float s2 = halfWaveSum(res * res);         // per-head ||.||^2 (C=1)
      if (m == 0) {
        qo[(size_t)row * Ec + t] = res;
        if ((t & 31) == 0) qno[(b * Hc + h) * Sc + s] = s2;
      } else {
        ko[(size_t)row * Ec + t] = res;
        if ((t & 31) == 0) kno[(b * Hc + h) * Sc + s] = s2;
      }
    } else {
      float vn2 = halfWaveSum(res * res);
      float vn = sqrtf(fmaxf(vn2, 1e-15f));
      float f = atanhf(fminf(vn, MAXNORM)) / vn;  // logmap0 factor
      lvo[(size_t)row * Ec + t] = f * res;
    }
  }
}

// ---------------------------------------------------------------------------
// Fused hyperbolic-distance attention, online softmax, expmap0.
// grid 512 = b(2) * h(8) * qtile(32, 16 rows each); block 256:
// r = tid&15 (q row in tile), g = tid>>4 (16-way j-split, 32 j each)
// ---------------------------------------------------------------------------
__global__ __launch_bounds__(256) void attn_kernel(
    const float* __restrict__ q, const float* __restrict__ k,
    const float* __restrict__ lv, const float* __restrict__ qn,
    const float* __restrict__ kn, const float* __restrict__ hs,
    float* __restrict__ out) {
  const int tid = threadIdx.x;
  const int r = tid & 15;
  const int g = tid >> 4;
  const int blk = blockIdx.x;
  const int qt = blk & 31;
  const int h = (blk >> 5) & 7;
  const int b = blk >> 8;
  const int sq = qt * 16 + r;

  const float* qrow = q + (size_t)(b * Sc + sq) * Ec + h * Dc;
  float4 qv[8];
#pragma unroll
  for (int i = 0; i < 8; ++i) qv[i] = ((const float4*)qrow)[i];
  const float q2 = qn[(b * Hc + h) * Sc + sq];
  const float sinv = -1.0f / (hs[h] * sqrtf((float)Dc));

  const float* kb = k + (size_t)(b * Sc) * Ec + h * Dc;
  const float* lvb = lv + (size_t)(b * Sc) * Ec + h * Dc;
  const float* knp = kn + (b * Hc + h) * Sc;

  float mM = -1e30f, lS = 0.0f;
  float4 acc4[8];
#pragma unroll
  for (int i = 0; i < 8; ++i) acc4[i] = make_float4(0.f, 0.f, 0.f, 0.f);

  for (int jj = 0; jj < 32; ++jj) {
    const int j = g * 32 + jj;
    const float4* kr = (const float4*)(kb + (size_t)j * Ec);
    const float4* lr = (const float4*)(lvb + (size_t)j * Ec);
    float4 kv[8], lvv[8];
#pragma unroll
    for (int i = 0; i < 8; ++i) kv[i] = kr[i];
#pragma unroll
    for (int i = 0; i < 8; ++i) lvv[i] = lr[i];
    float kq = 0.0f;
#pragma unroll
    for (int i = 0; i < 8; ++i) {
      kq = fmaf(qv[i].x, kv[i].x, kq);
      kq = fmaf(qv[i].y, kv[i].y, kq);
      kq = fmaf(qv[i].z, kv[i].z, kq);
      kq = fmaf(qv[i].w, kv[i].w, kq);
    }
    float k2 = knp[j];
    // ||mobius_add(-k,q)||^2 collapses to scalars of (kq, q2, k2)
    float A = 1.0f - 2.0f * kq + q2;
    float Bv = 1.0f - k2;
    float dden = 1.0f - 2.0f * kq + k2 * q2 + 1e-15f;
    float di = 1.0f / dden;
    float num2 = (A * A) * k2 - 2.0f * A * Bv * kq + (Bv * Bv) * q2;
    float dn = num2 * di * di;
    float denom = (1.0f - q2) * (1.0f - k2) + 1e-15f;
    float tt = fmaxf(2.0f * dn / denom, 1e-7f);        // a-1, cancellation-free
    float dist = log1pf(tt + sqrtf(tt * (2.0f + tt))); // acosh(1+tt)
    float sc = dist * sinv;
    float mn = fmaxf(mM, sc);
    float alpha = expf(mM - mn);
    float p = expf(sc - mn);
    lS = fmaf(lS, alpha, p);
#pragma unroll
    for (int i = 0; i < 8; ++i) {
      acc4[i].x = fmaf(acc4[i].x, alpha, p * lvv[i].x);
      acc4[i].y = fmaf(acc4[i].y, alpha, p * lvv[i].y);
      acc4[i].z = fmaf(acc4[i].z, alpha, p * lvv[i].z);
      acc4[i].w = fmaf(acc4[i].w, alpha, p * lvv[i].w);
    }
    mM = mn;
  }

  // merge 16 partials per row
  __shared__ float accb[16][16][36];  // [g][r][d], pad 36 for f4 align
  __shared__ float2 mlb[16][16];      // [r][g]
  __shared__ float cw[16][16];
  __shared__ float linvb[16];
  __shared__ float rowred[16][16];
  __shared__ float fscb[16];

  float* ap = &accb[g][r][0];
#pragma unroll
  for (int i = 0; i < 8; ++i) ((float4*)ap)[i] = acc4[i];
  mlb[r][g] = make_float2(mM, lS);
  __syncthreads();

  if (g == 0) {
    float M = mlb[r][0].x;
#pragma unroll
    for (int gg = 1; gg < 16; ++gg) M = fmaxf(M, mlb[r][gg].x);
    float L = 0.0f;
#pragma unroll
    for (int gg = 0; gg < 16; ++gg) {
      float wgt = expf(mlb[r][gg].x - M);
      cw[r][gg] = wgt;
      L = fmaf(mlb[r][gg].y, wgt, L);
    }
    linvb[r] = 1.0f / L;
  }
  __syncthreads();

  // thread (r,g) merges dims d = g*2, g*2+1
  float o0 = 0.f, o1 = 0.f;
#pragma unroll
  for (int gg = 0; gg < 16; ++gg) {
    float wgt = cw[r][gg];
    float2 p2 = *(const float2*)&accb[gg][r][g * 2];
    o0 = fmaf(p2.x, wgt, o0);
    o1 = fmaf(p2.y, wgt, o1);
  }
  float li = linvb[r];
  o0 *= li; o1 *= li;
  rowred[r][g] = o0 * o0 + o1 * o1;
  __syncthreads();
  if (g == 0) {
    float un2 = 0.0f;
#pragma unroll
    for (int gg = 0; gg < 16; ++gg) un2 += rowred[r][gg];
    float un = sqrtf(fmaxf(un2, 1e-15f));
    fscb[r] = tanhf(un) / un;   // expmap0 factor
  }
  __syncthreads();
  float f = fscb[r];
  float* orow = out + (size_t)(b * Sc + sq) * Ec + h * Dc + g * 2;
  orow[0] = o0 * f;
  orow[1] = o1 * f;
}

// ---------------------------------------------------------------------------
// Per-row hyp_linear epilogue for the output projection
// ---------------------------------------------------------------------------
__global__ __launch_bounds__(256) void proj_stats(
    const float* __restrict__ xin, const float* __restrict__ mx,
    const float* __restrict__ bo, float* __restrict__ out) {
  const int t = threadIdx.x;
  const int row = blockIdx.x;
  const float xv = xin[(size_t)row * Ec + t];
  const float m = mx[(size_t)row * Ec + t];
  const float bb = bo[t];
  float vals[4] = {xv * xv, m * m, m * bb, bb * bb};
  __shared__ float red[4][4];
  __shared__ float fin[4];
#pragma unroll
  for (int i = 0; i < 4; ++i) {
    float v = fullWaveSum(vals[i]);
    if ((t & 63) == 0) red[i][t >> 6] = v;
  }
  __syncthreads();
  if (t < 4) fin[t] = red[t][0] + red[t][1] + red[t][2] + red[t][3];
  __syncthreads();

  float x2 = fin[0], mx2 = fin[1], mxb = fin[2], b2 = fin[3];
  float xn = sqrtf(fmaxf(x2, 1e-15f));
  float mxn = sqrtf(fmaxf(mx2, 1e-15f));
  float scl = tanhf((mxn / xn) * atanhf(fminf(xn, MAXNORM))) / mxn;
  float mvv = scl * m;
  float X2 = scl * scl * mx2;
  float XY = scl * mxb;
  float numc = 1.0f + 2.0f * XY + b2;
  float den = 1.0f + 2.0f * XY + X2 * b2 + 1e-15f;
  out[(size_t)row * Ec + t] = (numc * mvv + (1.0f - X2) * bb) / den;
}

extern "C" void kernel_launch(void* const* d_in, const int* in_sizes, int n_in,
                              void* d_out, int out_size, void* d_ws, size_t ws_size,
                              hipStream_t stream) {
  (void)in_sizes; (void)n_in; (void)out_size; (void)ws_size;
  const float* x  = (const float*)d_in[0];
  const float* Wq = (const float*)d_in[1];
  const float* bq = (const float*)d_in[2];
  const float* Wk = (const float*)d_in[3];
  const float* bk = (const float*)d_in[4];
  const float* Wv = (const float*)d_in[5];
  const float* bv = (const float*)d_in[6];
  const float* Wo = (const float*)d_in[7];
  const float* bo = (const float*)d_in[8];
  const float* hs = (const float*)d_in[9];

  float* ws = (float*)d_ws;
  const int NE = Bc * Sc * Ec;   // 262144
  const int NH = Bc * Hc * Sc;   // 8192
  float* mxq = ws;
  float* mxk = mxq + NE;
  float* mxv = mxk + NE;
  float* qb  = mxv + NE;
  float* kb  = qb + NE;
  float* lvb = kb + NE;
  float* qnb = lvb + NE;
  float* knb = qnb + NH;
  float* aob = knb + NH;
  float* mxo = aob + NE;

  const int M = Bc * Sc;  // 1024 rows

  gemm_xwt<<<dim3(M / 32, 12), 128, 0, stream>>>(x, Wq, Wk, Wv, mxq, mxk, mxv);
  qkv_stats<<<M, 256, 0, stream>>>(x, mxq, mxk, mxv, bq, bk, bv,
                                   qb, kb, lvb, qnb, knb);
  attn_kernel<<<Bc * Hc * (Sc / 16), 256, 0, stream>>>(qb, kb, lvb, qnb, knb, hs, aob);
  gemm_xwt<<<dim3(M / 32, 4), 128, 0, stream>>>(aob, Wo, Wo, Wo, mxo, mxo, mxo);
  proj_stats<<<M, 256, 0, stream>>>(aob, mxo, bo, (float*)d_out);
}

// Round 3
// 145.803 us; speedup vs baseline: 1.3496x; 1.0880x over previous
//
#include <hip/hip_runtime.h>
#include <math.h>

#define Ec 256
#define Sc 512
#define Bc 2
#define Hc 8
#define Dc 32
#define MAXNORM (1.0f - 1e-5f)
#define NEc (Bc * Sc * Ec)

__device__ __forceinline__ float fullWaveSum(float v) {
#pragma unroll
  for (int m = 32; m >= 1; m >>= 1) v += __shfl_xor(v, m, 64);
  return v;
}
__device__ __forceinline__ float halfWaveSum(float v) {
#pragma unroll
  for (int m = 16; m >= 1; m >>= 1) v += __shfl_xor(v, m, 64);
  return v;
}
__device__ __forceinline__ float atanh_fast(float z) {   // z in [0, 1)
  return 0.5f * __logf((1.0f + z) / (1.0f - z));
}
__device__ __forceinline__ float tanh_fast(float a) {    // a >= 0
  float e = __expf(-2.0f * a);
  return (1.0f - e) / (1.0f + e);
}

// ---------------------------------------------------------------------------
// Tiled GEMM partial: O[kz] = X[:, kz*128:(kz+1)*128] @ W[:, same]^T
// Tile 32 rows x 64 cols, K-chunk 64. grid (M/32, 4*nmat, 2), block 128.
// ---------------------------------------------------------------------------
__global__ __launch_bounds__(128) void gemm_xwt(
    const float* __restrict__ X,
    const float* __restrict__ W0, const float* __restrict__ W1,
    const float* __restrict__ W2,
    float* __restrict__ O0, float* __restrict__ O1, float* __restrict__ O2) {
  const int tid = threadIdx.x;
  const int bx = blockIdx.x;
  const int by = blockIdx.y;
  const int kz = blockIdx.z;
  const int mat = by >> 2;
  const int cb0 = (by & 3) * 64;
  const int rb0 = bx * 32;
  const float* __restrict__ W = (mat == 0) ? W0 : (mat == 1) ? W1 : W2;
  float* __restrict__ O = ((mat == 0) ? O0 : (mat == 1) ? O1 : O2) + (size_t)kz * NEc;

  __shared__ float Xs[64][36];   // [k][row]
  __shared__ float Ws[64][68];   // [k][col]

  const int f4 = tid & 15;
  const int sub = tid >> 4;
  const int ty = tid >> 4;
  const int tx = tid & 15;

  float acc[4][4];
#pragma unroll
  for (int i = 0; i < 4; ++i)
#pragma unroll
    for (int j = 0; j < 4; ++j) acc[i][j] = 0.f;

  for (int kk = kz * 128; kk < kz * 128 + 128; kk += 64) {
    __syncthreads();
#pragma unroll
    for (int i = 0; i < 4; ++i) {
      int row = sub + i * 8;
      float4 v = *(const float4*)&X[(size_t)(rb0 + row) * Ec + kk + f4 * 4];
      Xs[f4 * 4 + 0][row] = v.x;
      Xs[f4 * 4 + 1][row] = v.y;
      Xs[f4 * 4 + 2][row] = v.z;
      Xs[f4 * 4 + 3][row] = v.w;
    }
#pragma unroll
    for (int i = 0; i < 8; ++i) {
      int col = sub + i * 8;
      float4 v = *(const float4*)&W[(size_t)(cb0 + col) * Ec + kk + f4 * 4];
      Ws[f4 * 4 + 0][col] = v.x;
      Ws[f4 * 4 + 1][col] = v.y;
      Ws[f4 * 4 + 2][col] = v.z;
      Ws[f4 * 4 + 3][col] = v.w;
    }
    __syncthreads();
#pragma unroll 8
    for (int k = 0; k < 64; ++k) {
      float4 a = *(const float4*)&Xs[k][ty * 4];
      float4 b = *(const float4*)&Ws[k][tx * 4];
      float av[4] = {a.x, a.y, a.z, a.w};
      float bv[4] = {b.x, b.y, b.z, b.w};
#pragma unroll
      for (int i = 0; i < 4; ++i)
#pragma unroll
        for (int j = 0; j < 4; ++j) acc[i][j] = fmaf(av[i], bv[j], acc[i][j]);
    }
  }
#pragma unroll
  for (int i = 0; i < 4; ++i) {
    float4 o = make_float4(acc[i][0], acc[i][1], acc[i][2], acc[i][3]);
    *(float4*)&O[(size_t)(rb0 + ty * 4 + i) * Ec + cb0 + tx * 4] = o;
  }
}

// ---------------------------------------------------------------------------
// Per-row hyp_linear epilogue for q/k/v (sums the 2 K-split partials)
// ---------------------------------------------------------------------------
__global__ __launch_bounds__(256) void qkv_stats(
    const float* __restrict__ x,
    const float* __restrict__ mxq, const float* __restrict__ mxk,
    const float* __restrict__ mxv,
    const float* __restrict__ bq, const float* __restrict__ bk,
    const float* __restrict__ bv,
    float* __restrict__ qo, float* __restrict__ ko, float* __restrict__ lvo,
    float* __restrict__ qno, float* __restrict__ kno) {
  const int t = threadIdx.x;
  const int row = blockIdx.x;
  const int b = row >> 9;
  const int s = row & (Sc - 1);
  const size_t idx = (size_t)row * Ec + t;
  const float xv = x[idx];
  const float mq = mxq[idx] + mxq[idx + NEc];
  const float mk = mxk[idx] + mxk[idx + NEc];
  const float mv = mxv[idx] + mxv[idx + NEc];
  const float bb[3] = {bq[t], bk[t], bv[t]};
  const float mvals[3] = {mq, mk, mv};

  float vals[10] = {xv * xv,
                    mq * mq, mq * bb[0], bb[0] * bb[0],
                    mk * mk, mk * bb[1], bb[1] * bb[1],
                    mv * mv, mv * bb[2], bb[2] * bb[2]};
  __shared__ float red[10][4];
  __shared__ float fin[10];
#pragma unroll
  for (int i = 0; i < 10; ++i) {
    float v = fullWaveSum(vals[i]);
    if ((t & 63) == 0) red[i][t >> 6] = v;
  }
  __syncthreads();
  if (t < 10) fin[t] = red[t][0] + red[t][1] + red[t][2] + red[t][3];
  __syncthreads();

  const float x2 = fin[0];
  const float xn = sqrtf(fmaxf(x2, 1e-15f));
  const float at = atanh_fast(fminf(xn, MAXNORM));  // SC = 1
  const int h = t >> 5;

#pragma unroll
  for (int m = 0; m < 3; ++m) {
    float mx2 = fin[1 + 3 * m];
    float mxb = fin[2 + 3 * m];
    float b2 = fin[3 + 3 * m];
    float mxn = sqrtf(fmaxf(mx2, 1e-15f));
    float scl = tanh_fast((mxn / xn) * at) / mxn;
    float mvv = scl * mvals[m];
    float X2 = scl * scl * mx2;
    float XY = scl * mxb;
    float numc = 1.0f + 2.0f * XY + b2;
    float den = 1.0f + 2.0f * XY + X2 * b2 + 1e-15f;
    float res = (numc * mvv + (1.0f - X2) * bb[m]) / den;
    if (m < 2) {
      res = fminf(res, MAXNORM);                 // elementwise clamp_max
      float s2 = halfWaveSum(res * res);         // per-head ||.||^2 (C=1)
      if (m == 0) {
        qo[idx] = res;
        if ((t & 31) == 0) qno[(b * Hc + h) * Sc + s] = s2;
      } else {
        ko[idx] = res;
        if ((t & 31) == 0) kno[(b * Hc + h) * Sc + s] = s2;
      }
    } else {
      float vn2 = halfWaveSum(res * res);
      float vn = sqrtf(fmaxf(vn2, 1e-15f));
      float f = atanh_fast(fminf(vn, MAXNORM)) / vn;  // logmap0 factor
      lvo[idx] = f * res;
    }
  }
}

// ---------------------------------------------------------------------------
// Fused hyperbolic-distance attention. No max-subtraction (scores in [-few,0]).
// grid 512 = b(2)*h(8)*qtile(32 of 16 rows); block 256:
//   rs = tid&7  -> q rows rs and rs+8 of the tile (2 rows/thread)
//   g  = tid>>3 -> 32 j-groups x 16 j each
// ---------------------------------------------------------------------------
__global__ __launch_bounds__(256, 2) void attn_kernel(
    const float* __restrict__ q, const float* __restrict__ k,
    const float* __restrict__ lv, const float* __restrict__ qn,
    const float* __restrict__ kn, const float* __restrict__ hs,
    float* __restrict__ out) {
  const int tid = threadIdx.x;
  const int rs = tid & 7;
  const int g = tid >> 3;
  const int blk = blockIdx.x;
  const int qt = blk & 31;
  const int h = (blk >> 5) & 7;
  const int b = blk >> 8;
  const int sq0 = qt * 16 + rs;

  const float* q0p = q + (size_t)(b * Sc + sq0) * Ec + h * Dc;
  const float* q1p = q0p + 8 * Ec;
  float4 qv0[8], qv1[8];
#pragma unroll
  for (int i = 0; i < 8; ++i) {
    qv0[i] = ((const float4*)q0p)[i];
    qv1[i] = ((const float4*)q1p)[i];
  }
  const float q20 = qn[(b * Hc + h) * Sc + sq0];
  const float q21 = qn[(b * Hc + h) * Sc + sq0 + 8];
  const float opq0 = 1.0f + q20, opq1 = 1.0f + q21;
  const float omq0 = 1.0f - q20, omq1 = 1.0f - q21;
  const float sinv = -1.0f / (hs[h] * sqrtf((float)Dc));

  const float* kbp = k + (size_t)(b * Sc) * Ec + h * Dc;
  const float* lvp = lv + (size_t)(b * Sc) * Ec + h * Dc;
  const float* knp = kn + (b * Hc + h) * Sc;

  float4 acc0[8], acc1[8];
#pragma unroll
  for (int i = 0; i < 8; ++i) {
    acc0[i] = make_float4(0.f, 0.f, 0.f, 0.f);
    acc1[i] = make_float4(0.f, 0.f, 0.f, 0.f);
  }
  float l0 = 0.f, l1 = 0.f;

#pragma unroll 1
  for (int jj = 0; jj < 16; ++jj) {
    const int j = g * 16 + jj;
    const float4* kr = (const float4*)(kbp + (size_t)j * Ec);
    const float4* lr = (const float4*)(lvp + (size_t)j * Ec);
    float4 kv[8], lvv[8];
#pragma unroll
    for (int i = 0; i < 8; ++i) kv[i] = kr[i];
    const float k2 = knp[j];
#pragma unroll
    for (int i = 0; i < 8; ++i) lvv[i] = lr[i];

    float kq0 = 0.f, kq1 = 0.f;
#pragma unroll
    for (int i = 0; i < 8; ++i) {
      kq0 = fmaf(qv0[i].x, kv[i].x, kq0);
      kq0 = fmaf(qv0[i].y, kv[i].y, kq0);
      kq0 = fmaf(qv0[i].z, kv[i].z, kq0);
      kq0 = fmaf(qv0[i].w, kv[i].w, kq0);
      kq1 = fmaf(qv1[i].x, kv[i].x, kq1);
      kq1 = fmaf(qv1[i].y, kv[i].y, kq1);
      kq1 = fmaf(qv1[i].z, kv[i].z, kq1);
      kq1 = fmaf(qv1[i].w, kv[i].w, kq1);
    }
    const float omk = 1.0f - k2;

    // row 0 score
    float A = fmaf(-2.0f, kq0, opq0);
    float dden = fmaf(k2, q20, fmaf(-2.0f, kq0, 1.0f)) + 1e-15f;
    float di = __builtin_amdgcn_rcpf(dden);
    float num2 = fmaf(A * A, k2, fmaf(-2.0f * A * omk, kq0, omk * omk * q20));
    float dn = num2 * di * di;
    float rd = __builtin_amdgcn_rcpf(fmaf(omq0, omk, 1e-15f));
    float tt = fmaxf(2.0f * dn * rd, 1e-7f);
    float z = 1.0f + tt + sqrtf(fmaf(tt, tt, 2.0f * tt));
    float p0 = __expf(sinv * __logf(z));
    // row 1 score
    A = fmaf(-2.0f, kq1, opq1);
    dden = fmaf(k2, q21, fmaf(-2.0f, kq1, 1.0f)) + 1e-15f;
    di = __builtin_amdgcn_rcpf(dden);
    num2 = fmaf(A * A, k2, fmaf(-2.0f * A * omk, kq1, omk * omk * q21));
    dn = num2 * di * di;
    rd = __builtin_amdgcn_rcpf(fmaf(omq1, omk, 1e-15f));
    tt = fmaxf(2.0f * dn * rd, 1e-7f);
    z = 1.0f + tt + sqrtf(fmaf(tt, tt, 2.0f * tt));
    float p1 = __expf(sinv * __logf(z));

    l0 += p0;
    l1 += p1;
#pragma unroll
    for (int i = 0; i < 8; ++i) {
      acc0[i].x = fmaf(p0, lvv[i].x, acc0[i].x);
      acc0[i].y = fmaf(p0, lvv[i].y, acc0[i].y);
      acc0[i].z = fmaf(p0, lvv[i].z, acc0[i].z);
      acc0[i].w = fmaf(p0, lvv[i].w, acc0[i].w);
      acc1[i].x = fmaf(p1, lvv[i].x, acc1[i].x);
      acc1[i].y = fmaf(p1, lvv[i].y, acc1[i].y);
      acc1[i].z = fmaf(p1, lvv[i].z, acc1[i].z);
      acc1[i].w = fmaf(p1, lvv[i].w, acc1[i].w);
    }
  }

  // merge 32 partials per row, two row-chunks (rows 0-7, then 8-15)
  __shared__ float accb[32][8][36];
  __shared__ float lsb[32][8];
  const int mr = tid >> 5;   // 0..7
  const int md = tid & 31;   // dim
  const size_t obase = (size_t)(b * Sc + qt * 16) * Ec + h * Dc + md;

#pragma unroll 1
  for (int chunk = 0; chunk < 2; ++chunk) {
    float* ap = &accb[g][rs][0];
#pragma unroll
    for (int i = 0; i < 8; ++i)
      ((float4*)ap)[i] = chunk ? acc1[i] : acc0[i];
    lsb[g][rs] = chunk ? l1 : l0;
    __syncthreads();

    float osum = 0.f, lsum = 0.f;
#pragma unroll
    for (int gg = 0; gg < 32; ++gg) {
      osum += accb[gg][mr][md];
      lsum += lsb[gg][mr];
    }
    float o = osum / lsum;
    float un2 = o * o;
#pragma unroll
    for (int m = 16; m >= 1; m >>= 1) un2 += __shfl_xor(un2, m, 32);
    float un = sqrtf(fmaxf(un2, 1e-15f));
    float f = tanh_fast(un) / un;   // expmap0 factor
    out[obase + (size_t)(chunk * 8 + mr) * Ec] = o * f;
    __syncthreads();
  }
}

// ---------------------------------------------------------------------------
// Per-row hyp_linear epilogue for the output projection (sums K-split partials)
// ---------------------------------------------------------------------------
__global__ __launch_bounds__(256) void proj_stats(
    const float* __restrict__ xin, const float* __restrict__ mx,
    const float* __restrict__ bo, float* __restrict__ out) {
  const int t = threadIdx.x;
  const int row = blockIdx.x;
  const size_t idx = (size_t)row * Ec + t;
  const float xv = xin[idx];
  const float m = mx[idx] + mx[idx + NEc];
  const float bb = bo[t];
  float vals[4] = {xv * xv, m * m, m * bb, bb * bb};
  __shared__ float red[4][4];
  __shared__ float fin[4];
#pragma unroll
  for (int i = 0; i < 4; ++i) {
    float v = fullWaveSum(vals[i]);
    if ((t & 63) == 0) red[i][t >> 6] = v;
  }
  __syncthreads();
  if (t < 4) fin[t] = red[t][0] + red[t][1] + red[t][2] + red[t][3];
  __syncthreads();

  float x2 = fin[0], mx2 = fin[1], mxb = fin[2], b2 = fin[3];
  float xn = sqrtf(fmaxf(x2, 1e-15f));
  float mxn = sqrtf(fmaxf(mx2, 1e-15f));
  float scl = tanh_fast((mxn / xn) * atanh_fast(fminf(xn, MAXNORM))) / mxn;
  float mvv = scl * m;
  float X2 = scl * scl * mx2;
  float XY = scl * mxb;
  float numc = 1.0f + 2.0f * XY + b2;
  float den = 1.0f + 2.0f * XY + X2 * b2 + 1e-15f;
  out[idx] = (numc * mvv + (1.0f - X2) * bb) / den;
}

extern "C" void kernel_launch(void* const* d_in, const int* in_sizes, int n_in,
                              void* d_out, int out_size, void* d_ws, size_t ws_size,
                              hipStream_t stream) {
  (void)in_sizes; (void)n_in; (void)out_size; (void)ws_size;
  const float* x  = (const float*)d_in[0];
  const float* Wq = (const float*)d_in[1];
  const float* bq = (const float*)d_in[2];
  const float* Wk = (const float*)d_in[3];
  const float* bk = (const float*)d_in[4];
  const float* Wv = (const float*)d_in[5];
  const float* bv = (const float*)d_in[6];
  const float* Wo = (const float*)d_in[7];
  const float* bo = (const float*)d_in[8];
  const float* hs = (const float*)d_in[9];

  float* ws = (float*)d_ws;
  const int NE = NEc;            // 262144
  const int NH = Bc * Hc * Sc;   // 8192
  float* mxq = ws;               // 2*NE (k-split partials)
  float* mxk = mxq + 2 * NE;
  float* mxv = mxk + 2 * NE;
  float* qb  = mxv + 2 * NE;
  float* kb  = qb + NE;
  float* lvb = kb + NE;
  float* qnb = lvb + NE;
  float* knb = qnb + NH;
  float* aob = knb + NH;
  float* mxo = aob + NE;         // 2*NE

  const int M = Bc * Sc;  // 1024 rows

  gemm_xwt<<<dim3(M / 32, 12, 2), 128, 0, stream>>>(x, Wq, Wk, Wv, mxq, mxk, mxv);
  qkv_stats<<<M, 256, 0, stream>>>(x, mxq, mxk, mxv, bq, bk, bv,
                                   qb, kb, lvb, qnb, knb);
  attn_kernel<<<512, 256, 0, stream>>>(qb, kb, lvb, qnb, knb, hs, aob);
  gemm_xwt<<<dim3(M / 32, 4, 2), 128, 0, stream>>>(aob, Wo, Wo, Wo, mxo, mxo, mxo);
  proj_stats<<<M, 256, 0, stream>>>(aob, mxo, bo, (float*)d_out);
}

// Round 4
// 142.699 us; speedup vs baseline: 1.3790x; 1.0218x over previous
//
#include <hip/hip_runtime.h>
#include <math.h>

#define Ec 256
#define Sc 512
#define Bc 2
#define Hc 8
#define Dc 32
#define MAXNORM (1.0f - 1e-5f)
#define NEc (Bc * Sc * Ec)
#define KSPLIT 4

__device__ __forceinline__ float fullWaveSum(float v) {
#pragma unroll
  for (int m = 32; m >= 1; m >>= 1) v += __shfl_xor(v, m, 64);
  return v;
}
__device__ __forceinline__ float halfWaveSum(float v) {
#pragma unroll
  for (int m = 16; m >= 1; m >>= 1) v += __shfl_xor(v, m, 64);
  return v;
}
__device__ __forceinline__ float atanh_fast(float z) {   // z in [0, 1)
  return 0.5f * __logf((1.0f + z) / (1.0f - z));
}
__device__ __forceinline__ float tanh_fast(float a) {    // a >= 0
  float e = __expf(-2.0f * a);
  return (1.0f - e) / (1.0f + e);
}

// ---------------------------------------------------------------------------
// Tiled GEMM partial: O[kz] = X[:, kz*64:(kz+1)*64] @ W[:, same]^T
// Tile 32 rows x 64 cols, single K-chunk of 64. grid (M/32, 4*nmat, 4), blk 128
// ---------------------------------------------------------------------------
__global__ __launch_bounds__(128) void gemm_xwt(
    const float* __restrict__ X,
    const float* __restrict__ W0, const float* __restrict__ W1,
    const float* __restrict__ W2,
    float* __restrict__ O0, float* __restrict__ O1, float* __restrict__ O2) {
  const int tid = threadIdx.x;
  const int bx = blockIdx.x;
  const int by = blockIdx.y;
  const int kz = blockIdx.z;
  const int mat = by >> 2;
  const int cb0 = (by & 3) * 64;
  const int rb0 = bx * 32;
  const int kk = kz * 64;
  const float* __restrict__ W = (mat == 0) ? W0 : (mat == 1) ? W1 : W2;
  float* __restrict__ O = ((mat == 0) ? O0 : (mat == 1) ? O1 : O2) + (size_t)kz * NEc;

  __shared__ float Xs[64][36];   // [k][row]
  __shared__ float Ws[64][68];   // [k][col]

  const int f4 = tid & 15;
  const int sub = tid >> 4;
  const int ty = tid >> 4;
  const int tx = tid & 15;

#pragma unroll
  for (int i = 0; i < 4; ++i) {
    int row = sub + i * 8;
    float4 v = *(const float4*)&X[(size_t)(rb0 + row) * Ec + kk + f4 * 4];
    Xs[f4 * 4 + 0][row] = v.x;
    Xs[f4 * 4 + 1][row] = v.y;
    Xs[f4 * 4 + 2][row] = v.z;
    Xs[f4 * 4 + 3][row] = v.w;
  }
#pragma unroll
  for (int i = 0; i < 8; ++i) {
    int col = sub + i * 8;
    float4 v = *(const float4*)&W[(size_t)(cb0 + col) * Ec + kk + f4 * 4];
    Ws[f4 * 4 + 0][col] = v.x;
    Ws[f4 * 4 + 1][col] = v.y;
    Ws[f4 * 4 + 2][col] = v.z;
    Ws[f4 * 4 + 3][col] = v.w;
  }
  __syncthreads();

  float acc[4][4];
#pragma unroll
  for (int i = 0; i < 4; ++i)
#pragma unroll
    for (int j = 0; j < 4; ++j) acc[i][j] = 0.f;

#pragma unroll 8
  for (int k = 0; k < 64; ++k) {
    float4 a = *(const float4*)&Xs[k][ty * 4];
    float4 b = *(const float4*)&Ws[k][tx * 4];
    float av[4] = {a.x, a.y, a.z, a.w};
    float bv[4] = {b.x, b.y, b.z, b.w};
#pragma unroll
    for (int i = 0; i < 4; ++i)
#pragma unroll
      for (int j = 0; j < 4; ++j) acc[i][j] = fmaf(av[i], bv[j], acc[i][j]);
  }
#pragma unroll
  for (int i = 0; i < 4; ++i) {
    float4 o = make_float4(acc[i][0], acc[i][1], acc[i][2], acc[i][3]);
    *(float4*)&O[(size_t)(rb0 + ty * 4 + i) * Ec + cb0 + tx * 4] = o;
  }
}

// ---------------------------------------------------------------------------
// Per-row hyp_linear epilogue for q/k/v (sums the 4 K-split partials)
// ---------------------------------------------------------------------------
__global__ __launch_bounds__(256) void qkv_stats(
    const float* __restrict__ x,
    const float* __restrict__ mxq, const float* __restrict__ mxk,
    const float* __restrict__ mxv,
    const float* __restrict__ bq, const float* __restrict__ bk,
    const float* __restrict__ bv,
    float* __restrict__ qo, float* __restrict__ ko, float* __restrict__ lvo,
    float* __restrict__ qno, float* __restrict__ kno) {
  const int t = threadIdx.x;
  const int row = blockIdx.x;
  const int b = row >> 9;
  const int s = row & (Sc - 1);
  const size_t idx = (size_t)row * Ec + t;
  const float xv = x[idx];
  float mq = 0.f, mk = 0.f, mv = 0.f;
#pragma unroll
  for (int p = 0; p < KSPLIT; ++p) {
    mq += mxq[idx + (size_t)p * NEc];
    mk += mxk[idx + (size_t)p * NEc];
    mv += mxv[idx + (size_t)p * NEc];
  }
  const float bb[3] = {bq[t], bk[t], bv[t]};
  const float mvals[3] = {mq, mk, mv};

  float vals[10] = {xv * xv,
                    mq * mq, mq * bb[0], bb[0] * bb[0],
                    mk * mk, mk * bb[1], bb[1] * bb[1],
                    mv * mv, mv * bb[2], bb[2] * bb[2]};
  __shared__ float red[10][4];
  __shared__ float fin[10];
#pragma unroll
  for (int i = 0; i < 10; ++i) {
    float v = fullWaveSum(vals[i]);
    if ((t & 63) == 0) red[i][t >> 6] = v;
  }
  __syncthreads();
  if (t < 10) fin[t] = red[t][0] + red[t][1] + red[t][2] + red[t][3];
  __syncthreads();

  const float x2 = fin[0];
  const float xn = sqrtf(fmaxf(x2, 1e-15f));
  const float at = atanh_fast(fminf(xn, MAXNORM));  // SC = 1
  const int h = t >> 5;

#pragma unroll
  for (int m = 0; m < 3; ++m) {
    float mx2 = fin[1 + 3 * m];
    float mxb = fin[2 + 3 * m];
    float b2 = fin[3 + 3 * m];
    float mxn = sqrtf(fmaxf(mx2, 1e-15f));
    float scl = tanh_fast((mxn / xn) * at) / mxn;
    float mvv = scl * mvals[m];
    float X2 = scl * scl * mx2;
    float XY = scl * mxb;
    float numc = 1.0f + 2.0f * XY + b2;
    float den = 1.0f + 2.0f * XY + X2 * b2 + 1e-15f;
    float res = (numc * mvv + (1.0f - X2) * bb[m]) / den;
    if (m < 2) {
      res = fminf(res, MAXNORM);                 // elementwise clamp_max
      float s2 = halfWaveSum(res * res);         // per-head ||.||^2 (C=1)
      if (m == 0) {
        qo[idx] = res;
        if ((t & 31) == 0) qno[(b * Hc + h) * Sc + s] = s2;
      } else {
        ko[idx] = res;
        if ((t & 31) == 0) kno[(b * Hc + h) * Sc + s] = s2;
      }
    } else {
      float vn2 = halfWaveSum(res * res);
      float vn = sqrtf(fmaxf(vn2, 1e-15f));
      float f = atanh_fast(fminf(vn, MAXNORM)) / vn;  // logmap0 factor
      lvo[idx] = f * res;
    }
  }
}

// ---------------------------------------------------------------------------
// Fused hyperbolic-distance attention. No max-subtraction (scores in [-few,0]).
// grid 1024 = b(2)*h(8)*qtile(64 of 8 rows); block 256:
//   rs = tid&7  -> q row in tile (1 row/thread)
//   g  = tid>>3 -> 32 j-groups x 16 j each
// Merge: half-size LDS buffer, 3 phases, no runtime-conditional array access
// (R3's spill came from exactly that).
// ---------------------------------------------------------------------------
__global__ __launch_bounds__(256) void attn_kernel(
    const float* __restrict__ q, const float* __restrict__ k,
    const float* __restrict__ lv, const float* __restrict__ qn,
    const float* __restrict__ kn, const float* __restrict__ hs,
    float* __restrict__ out) {
  const int tid = threadIdx.x;
  const int rs = tid & 7;
  const int g = tid >> 3;
  const int blk = blockIdx.x;
  const int qt = blk & 63;
  const int h = (blk >> 6) & 7;
  const int b = blk >> 9;
  const int sq = qt * 8 + rs;

  const float* qrow = q + (size_t)(b * Sc + sq) * Ec + h * Dc;
  float4 qv[8];
#pragma unroll
  for (int i = 0; i < 8; ++i) qv[i] = ((const float4*)qrow)[i];
  const float q2 = qn[(b * Hc + h) * Sc + sq];
  const float opq = 1.0f + q2;
  const float omq = 1.0f - q2;
  const float sinv = -1.0f / (hs[h] * sqrtf((float)Dc));

  const float* kbp = k + (size_t)(b * Sc) * Ec + h * Dc;
  const float* lvp = lv + (size_t)(b * Sc) * Ec + h * Dc;
  const float* knp = kn + (b * Hc + h) * Sc;

  float4 acc[8];
#pragma unroll
  for (int i = 0; i < 8; ++i) acc[i] = make_float4(0.f, 0.f, 0.f, 0.f);
  float l = 0.f;

#pragma unroll 1
  for (int jj = 0; jj < 16; ++jj) {
    const int j = g * 16 + jj;
    const float4* kr = (const float4*)(kbp + (size_t)j * Ec);
    float4 kv[8];
#pragma unroll
    for (int i = 0; i < 8; ++i) kv[i] = kr[i];
    const float k2 = knp[j];

    float kq = 0.f;
#pragma unroll
    for (int i = 0; i < 8; ++i) {
      kq = fmaf(qv[i].x, kv[i].x, kq);
      kq = fmaf(qv[i].y, kv[i].y, kq);
      kq = fmaf(qv[i].z, kv[i].z, kq);
      kq = fmaf(qv[i].w, kv[i].w, kq);
    }
    const float omk = 1.0f - k2;
    float A = fmaf(-2.0f, kq, opq);
    float dden = fmaf(k2, q2, fmaf(-2.0f, kq, 1.0f)) + 1e-15f;
    float di = __builtin_amdgcn_rcpf(dden);
    float num2 = fmaf(A * A, k2, fmaf(-2.0f * A * omk, kq, omk * omk * q2));
    float dn = num2 * di * di;
    float rd = __builtin_amdgcn_rcpf(fmaf(omq, omk, 1e-15f));
    float tt = fmaxf(2.0f * dn * rd, 1e-7f);
    float z = 1.0f + tt + sqrtf(fmaf(tt, tt, 2.0f * tt));
    float p = __expf(sinv * __logf(z));
    l += p;

    const float4* lr = (const float4*)(lvp + (size_t)j * Ec);
#pragma unroll
    for (int i = 0; i < 8; ++i) {
      float4 lvv = lr[i];
      acc[i].x = fmaf(p, lvv.x, acc[i].x);
      acc[i].y = fmaf(p, lvv.y, acc[i].y);
      acc[i].z = fmaf(p, lvv.z, acc[i].z);
      acc[i].w = fmaf(p, lvv.w, acc[i].w);
    }
  }

  // ---- merge 32 partials per row via half-size buffer (3 phases) ----
  __shared__ float accb[16][8][36];
  __shared__ float lsb[16][8];

  if (g >= 16) {
    float* ap = &accb[g - 16][rs][0];
#pragma unroll
    for (int i = 0; i < 8; ++i) ((float4*)ap)[i] = acc[i];
    lsb[g - 16][rs] = l;
  }
  __syncthreads();
  if (g < 16) {
    float* ap = &accb[g][rs][0];
#pragma unroll
    for (int i = 0; i < 8; ++i) {
      float4 t = ((float4*)ap)[i];
      t.x += acc[i].x; t.y += acc[i].y; t.z += acc[i].z; t.w += acc[i].w;
      ((float4*)ap)[i] = t;
    }
    lsb[g][rs] += l;
  }
  __syncthreads();

  // reduce 16 slots: thread (mr, md) handles row mr, dim md
  const int mr = tid >> 5;   // 0..7
  const int md = tid & 31;   // 0..31
  float osum = 0.f, lsum = 0.f;
#pragma unroll
  for (int gg = 0; gg < 16; ++gg) {
    osum += accb[gg][mr][md];
    lsum += lsb[gg][mr];
  }
  float o = osum / lsum;
  float un2 = o * o;
#pragma unroll
  for (int m = 16; m >= 1; m >>= 1) un2 += __shfl_xor(un2, m, 32);
  float un = sqrtf(fmaxf(un2, 1e-15f));
  float f = tanh_fast(un) / un;   // expmap0 factor
  out[(size_t)(b * Sc + qt * 8 + mr) * Ec + h * Dc + md] = o * f;
}

// ---------------------------------------------------------------------------
// Per-row hyp_linear epilogue for the output projection (sums K-split partials)
// ---------------------------------------------------------------------------
__global__ __launch_bounds__(256) void proj_stats(
    const float* __restrict__ xin, const float* __restrict__ mx,
    const float* __restrict__ bo, float* __restrict__ out) {
  const int t = threadIdx.x;
  const int row = blockIdx.x;
  const size_t idx = (size_t)row * Ec + t;
  const float xv = xin[idx];
  float m = 0.f;
#pragma unroll
  for (int p = 0; p < KSPLIT; ++p) m += mx[idx + (size_t)p * NEc];
  const float bb = bo[t];
  float vals[4] = {xv * xv, m * m, m * bb, bb * bb};
  __shared__ float red[4][4];
  __shared__ float fin[4];
#pragma unroll
  for (int i = 0; i < 4; ++i) {
    float v = fullWaveSum(vals[i]);
    if ((t & 63) == 0) red[i][t >> 6] = v;
  }
  __syncthreads();
  if (t < 4) fin[t] = red[t][0] + red[t][1] + red[t][2] + red[t][3];
  __syncthreads();

  float x2 = fin[0], mx2 = fin[1], mxb = fin[2], b2 = fin[3];
  float xn = sqrtf(fmaxf(x2, 1e-15f));
  float mxn = sqrtf(fmaxf(mx2, 1e-15f));
  float scl = tanh_fast((mxn / xn) * atanh_fast(fminf(xn, MAXNORM))) / mxn;
  float mvv = scl * m;
  float X2 = scl * scl * mx2;
  float XY = scl * mxb;
  float numc = 1.0f + 2.0f * XY + b2;
  float den = 1.0f + 2.0f * XY + X2 * b2 + 1e-15f;
  out[idx] = (numc * mvv + (1.0f - X2) * bb) / den;
}

extern "C" void kernel_launch(void* const* d_in, const int* in_sizes, int n_in,
                              void* d_out, int out_size, void* d_ws, size_t ws_size,
                              hipStream_t stream) {
  (void)in_sizes; (void)n_in; (void)out_size; (void)ws_size;
  const float* x  = (const float*)d_in[0];
  const float* Wq = (const float*)d_in[1];
  const float* bq = (const float*)d_in[2];
  const float* Wk = (const float*)d_in[3];
  const float* bk = (const float*)d_in[4];
  const float* Wv = (const float*)d_in[5];
  const float* bv = (const float*)d_in[6];
  const float* Wo = (const float*)d_in[7];
  const float* bo = (const float*)d_in[8];
  const float* hs = (const float*)d_in[9];

  float* ws = (float*)d_ws;
  const int NE = NEc;            // 262144
  const int NH = Bc * Hc * Sc;   // 8192
  float* mxq = ws;               // KSPLIT*NE partials each
  float* mxk = mxq + KSPLIT * NE;
  float* mxv = mxk + KSPLIT * NE;
  float* mxo = mxv + KSPLIT * NE;
  float* qb  = mxo + KSPLIT * NE;
  float* kb  = qb + NE;
  float* lvb = kb + NE;
  float* aob = lvb + NE;
  float* qnb = aob + NE;
  float* knb = qnb + NH;

  const int M = Bc * Sc;  // 1024 rows

  gemm_xwt<<<dim3(M / 32, 12, KSPLIT), 128, 0, stream>>>(x, Wq, Wk, Wv, mxq, mxk, mxv);
  qkv_stats<<<M, 256, 0, stream>>>(x, mxq, mxk, mxv, bq, bk, bv,
                                   qb, kb, lvb, qnb, knb);
  attn_kernel<<<1024, 256, 0, stream>>>(qb, kb, lvb, qnb, knb, hs, aob);
  gemm_xwt<<<dim3(M / 32, 4, KSPLIT), 128, 0, stream>>>(aob, Wo, Wo, Wo, mxo, mxo, mxo);
  proj_stats<<<M, 256, 0, stream>>>(aob, mxo, bo, (float*)d_out);
}